// Round 8
// baseline (159.736 us; speedup 1.0000x reference)
//
#include <hip/hip_runtime.h>

#define S_LEN 1024
#define NHEAD 12
#define SCALE 0.125f
#define INF_ 1000000.0f

typedef __attribute__((ext_vector_type(8))) short bfrag;
typedef __attribute__((ext_vector_type(4))) float f32x4;
typedef unsigned short ushort_t;
typedef unsigned int uint_t;
typedef unsigned long long u64_t;

__device__ inline ushort_t f2bf(float f) {
    union { float f; uint_t u; } v; v.f = f;
    uint_t u = v.u;
    return (ushort_t)((u + 0x7fffu + ((u >> 16) & 1u)) >> 16);
}
__device__ inline float bf2f(ushort_t h) {
    union { uint_t u; float f; } v; v.u = ((uint_t)h) << 16;
    return v.f;
}

// ---------------- mask pre-pack: clsb bf16 + tt u64 ballot bits ----------
__global__ __launch_bounds__(256) void pack_masks(
    const float* __restrict__ cls, const int* __restrict__ tt,
    ushort_t* __restrict__ clsb, u64_t* __restrict__ ttb)
{
    int i = blockIdx.x, b = blockIdx.y, tid = threadIdx.x;
    int wave = tid >> 6, lane = tid & 63;
    if (b == 0) {
        for (int j = tid; j < 1024; j += 256)
            clsb[(size_t)i * 1024 + j] = f2bf(cls[(size_t)i * 1024 + j]);
    }
#pragma unroll
    for (int l = 0; l < 4; ++l) {
        int j = l * 256 + tid;
        int v = tt[((size_t)b * 1024 + i) * 1024 + j];
        u64_t m = __ballot(v != 0);
        if (lane == 0) ttb[((size_t)b * 1024 + i) * 16 + l * 4 + wave] = m;
    }
}

// ---------------- weight transpose+convert (batched) ---------------------
struct TJobs { const float* src[5]; ushort_t* dst[5]; };
__global__ __launch_bounds__(256) void tcvt_multi(TJobs jobs) {
    __shared__ float tile[64][65];
    const float* src = jobs.src[blockIdx.z];
    ushort_t* dst = jobs.dst[blockIdx.z];
    int bx = blockIdx.x * 64, by = blockIdx.y * 64;
    for (int e = threadIdx.x; e < 4096; e += 256) {
        int r = e >> 6, c = e & 63;
        tile[r][c] = src[(size_t)(by + r) * 768 + bx + c];
    }
    __syncthreads();
    for (int e = threadIdx.x; e < 4096; e += 256) {
        int r = e >> 6, c = e & 63;
        dst[(size_t)(bx + r) * 768 + by + c] = f2bf(tile[c][r]);
    }
}

// ---------------- batched bf16 MFMA GEMM (register-prefetched) -----------
struct GemmJob {
    const float* Af; const ushort_t* Ah; const ushort_t* BT;
    const float* bias; const float* bias2; const float* bias3;
    float* Cf; ushort_t* Ch; ushort_t* Ch2; ushort_t* Ch3;
    float scale; int mode;
};
struct GemmJobs4 { GemmJob j[4]; };

__global__ __launch_bounds__(256) void gemm_batch(GemmJobs4 jobs) {
    GemmJob jb = jobs.j[blockIdx.z];
    __shared__ __align__(16) ushort_t As[64 * 40];
    __shared__ __align__(16) ushort_t Bs[64 * 40];
    int tid = threadIdx.x;
    int w = tid >> 6, lane = tid & 63, l15 = lane & 15, l4 = lane >> 4;
    int rowBase = blockIdx.x * 64, colBase = blockIdx.y * 64;
    int wm = w >> 1, wn = w & 1;
    f32x4 acc[2][2] = {{{0,0,0,0},{0,0,0,0}},{{0,0,0,0},{0,0,0,0}}};
    int srow = tid >> 2, schunk = (tid & 3) * 8;
    const bool cvt = (jb.Ah == nullptr);

    float4 fa0, fa1; uint4 ra, rb;
    if (cvt) {
        const float* ap = &jb.Af[(size_t)(rowBase + srow) * 768 + schunk];
        fa0 = *(const float4*)ap; fa1 = *(const float4*)(ap + 4);
    } else {
        ra = *(const uint4*)&jb.Ah[(size_t)(rowBase + srow) * 768 + schunk];
    }
    rb = *(const uint4*)&jb.BT[(size_t)(colBase + srow) * 768 + schunk];

    for (int k0 = 0; k0 < 768; k0 += 32) {
        __syncthreads();
        if (cvt) {
            ushort_t tmp[8] = {f2bf(fa0.x), f2bf(fa0.y), f2bf(fa0.z), f2bf(fa0.w),
                               f2bf(fa1.x), f2bf(fa1.y), f2bf(fa1.z), f2bf(fa1.w)};
            *(uint4*)&As[srow * 40 + schunk] = *(const uint4*)tmp;
        } else {
            *(uint4*)&As[srow * 40 + schunk] = ra;
        }
        *(uint4*)&Bs[srow * 40 + schunk] = rb;
        __syncthreads();
        int kn = k0 + 32;
        if (kn < 768) {
            if (cvt) {
                const float* ap = &jb.Af[(size_t)(rowBase + srow) * 768 + kn + schunk];
                fa0 = *(const float4*)ap; fa1 = *(const float4*)(ap + 4);
            } else {
                ra = *(const uint4*)&jb.Ah[(size_t)(rowBase + srow) * 768 + kn + schunk];
            }
            rb = *(const uint4*)&jb.BT[(size_t)(colBase + srow) * 768 + kn + schunk];
        }
        bfrag bfr[2];
#pragma unroll
        for (int nf = 0; nf < 2; ++nf)
            bfr[nf] = *(const bfrag*)&Bs[(wn * 32 + nf * 16 + l15) * 40 + l4 * 8];
#pragma unroll
        for (int mf = 0; mf < 2; ++mf) {
            bfrag af = *(const bfrag*)&As[(wm * 32 + mf * 16 + l15) * 40 + l4 * 8];
#pragma unroll
            for (int nf = 0; nf < 2; ++nf)
                acc[mf][nf] = __builtin_amdgcn_mfma_f32_16x16x32_bf16(af, bfr[nf], acc[mf][nf], 0, 0, 0);
        }
    }
#pragma unroll
    for (int mf = 0; mf < 2; ++mf)
#pragma unroll
        for (int nf = 0; nf < 2; ++nf)
#pragma unroll
            for (int rg = 0; rg < 4; ++rg) {
                int row = rowBase + wm * 32 + mf * 16 + l4 * 4 + rg;
                int col = colBase + wn * 32 + nf * 16 + l15;
                float base = acc[mf][nf][rg];
                if (jb.mode == 3) {
                    size_t idx = (size_t)row * 768 + col;
                    jb.Ch [idx] = f2bf((base + jb.bias [col]) * jb.scale);
                    jb.Ch2[idx] = f2bf((base + jb.bias2[col]) * jb.scale);
                    jb.Ch3[idx] = f2bf((base + jb.bias3[col]) * jb.scale);
                } else {
                    float v = base * jb.scale + (jb.bias ? jb.bias[col] : 0.0f);
                    if (jb.mode == 0) jb.Cf[(size_t)row * 768 + col] = v;
                    else if (jb.mode == 1) jb.Ch[(size_t)row * 768 + col] = f2bf(v);
                    else jb.Ch[((size_t)(row >> 10) * 768 + col) * 1024 + (row & 1023)] = f2bf(v);
                }
            }
}

// ---------------- fused attention: 6 heads/block, LDS-cached masks -------
// grid 256 (1-D), block 512 (8 waves). Block = (b, head-group of 6, 16 rows).
// Wave w owns j in [w*128, w*128+128) during score phase.
__global__ __launch_bounds__(512) void attn_mfma(
    const ushort_t* __restrict__ qw,   // (B*S,768) bf16 (q + rwb*scale)
    const ushort_t* __restrict__ qr,   // (B*S,768) bf16 (q + rrb*scale)
    const ushort_t* __restrict__ qs,   // (B*S,768) bf16 (q + rsb*scale)
    const ushort_t* __restrict__ kh,   // (B*S,768) bf16
    const ushort_t* __restrict__ vt,   // (B,768,S) bf16
    const ushort_t* __restrict__ rh,   // (2064,768) bf16
    const float* __restrict__ seg,     // (2,768)
    const ushort_t* __restrict__ clsb, // (S,S) bf16
    const u64_t* __restrict__ ttb,     // (B,S,16) bitmask
    const int* __restrict__ amask,     // (B,S)
    ushort_t* __restrict__ av)         // (B*S,768) bf16
{
    __shared__ __align__(16) ushort_t sS[16 * 1024];    // 32KB scores
    __shared__ __align__(16) ushort_t sCls[16 * 1024];  // 32KB cls (swizzled)
    __shared__ u64_t sTT[16 * 16];                      // 2KB tt bits
    __shared__ __align__(8) ushort_t sAm[1024];         // 2KB
    __shared__ float sPV[2][16][64];                    // 8KB partial PV
    __shared__ float sDiff[16], sSame[16];
    __shared__ float sMax[16 * 8];
    __shared__ float sSum[16];

    const int tid = threadIdx.x;
    const int w = tid >> 6, lane = tid & 63;
    const int l15 = lane & 15, l4 = lane >> 4;

    // block decode: xcd = bid&7 -> (b, head-group, i0-half); local = bid>>3
    const int bid = blockIdx.x;
    const int xcd = bid & 7;
    const int b  = xcd >> 2;
    const int hg = (xcd >> 1) & 1;
    const int i0 = ((((xcd & 1) << 5) | (bid >> 3))) << 4;

    const int jbase = w * 128;
    const int tstart = 1009 - i0;  // S - i0 - 15

    // ---- stage masks ONCE (shared by all 6 heads) ----
    for (int e = tid * 8; e < 16 * 1024; e += 512 * 8) {
        int row = e >> 10, j8 = e & 1023;
        uint4 v = *(const uint4*)&clsb[(size_t)(i0 + row) * 1024 + j8];
        *(uint4*)&sCls[row * 1024 + (j8 ^ ((row & 7) << 3))] = v;
    }
    if (tid < 256)
        sTT[tid] = ttb[((size_t)b * 1024 + i0 + (tid >> 4)) * 16 + (tid & 15)];
    if (tid < 256) {
        int j4 = tid * 4;
        int4 a4 = *(const int4*)&amask[b * S_LEN + j4];
        sAm[j4 + 0] = f2bf(-INF_ * (1.0f - (float)a4.x));
        sAm[j4 + 1] = f2bf(-INF_ * (1.0f - (float)a4.y));
        sAm[j4 + 2] = f2bf(-INF_ * (1.0f - (float)a4.z));
        sAm[j4 + 3] = f2bf(-INF_ * (1.0f - (float)a4.w));
    }

    // combine helper state
    for (int g = 0; g < 6; ++g) {
        const int n = hg * 6 + g;
        const size_t qoff = (size_t)(b * S_LEN + i0) * 768 + n * 64;

        // ---- combine previous head's PV partials (after its last barrier) --
        if (g > 0) {
            const int npv = hg * 6 + g - 1;
            int e = tid * 2;
            int row = e >> 6, col = e & 63;
            float inv = 1.0f / sSum[row];
            float v0 = (sPV[0][row][col] + sPV[1][row][col]) * inv;
            float v1 = (sPV[0][row][col + 1] + sPV[1][row][col + 1]) * inv;
            uint_t pk = (uint_t)f2bf(v0) | ((uint_t)f2bf(v1) << 16);
            *(uint_t*)&av[(size_t)(b * S_LEN + i0 + row) * 768 + npv * 64 + col] = pk;
        }

        // ---- Q fragments for this head ----
        bfrag aQw0 = *(const bfrag*)&qw[qoff + (size_t)l15 * 768 + l4 * 8];
        bfrag aQw1 = *(const bfrag*)&qw[qoff + (size_t)l15 * 768 + 32 + l4 * 8];
        bfrag aQr0 = *(const bfrag*)&qr[qoff + (size_t)l15 * 768 + l4 * 8];
        bfrag aQr1 = *(const bfrag*)&qr[qoff + (size_t)l15 * 768 + 32 + l4 * 8];

        // ---- seg dots: wave w handles rows w*2, w*2+1 ----
        {
            float s0 = seg[n * 64 + lane], s1 = seg[768 + n * 64 + lane];
#pragma unroll
            for (int rr = 0; rr < 2; ++rr) {
                int r = w * 2 + rr;
                float qsv = bf2f(qs[qoff + (size_t)r * 768 + lane]);
                float d = qsv * s0, sm2 = qsv * s1;
#pragma unroll
                for (int off = 32; off >= 1; off >>= 1) {
                    d += __shfl_xor(d, off);
                    sm2 += __shfl_xor(sm2, off);
                }
                if (lane == 0) { sDiff[r] = d; sSame[r] = sm2; }
            }
        }
        __syncthreads();  // B1: masks (g==0), sDiff ready; sS free (prev PV done)

        // ---- score phase: merged pos/content over wave's 128-col stripe --
        {
            float diffR[4], sameR[4];
#pragma unroll
            for (int rg = 0; rg < 4; ++rg) {
                int il = l4 * 4 + rg;
                diffR[rg] = sDiff[il];
                sameR[rg] = sSame[il];
            }
            float vmax[4] = {-3.0e38f, -3.0e38f, -3.0e38f, -3.0e38f};
            bfrag rC0, rC1, kC0, kC1, kP0, kP1;
            {
                const ushort_t* rp = &rh[(size_t)(tstart + jbase + l15) * 768 + n * 64 + l4 * 8];
                rC0 = *(const bfrag*)rp; rC1 = *(const bfrag*)(rp + 32);
            }
            {
                const ushort_t* kp = &kh[(size_t)(b * S_LEN + jbase + l15) * 768 + n * 64 + l4 * 8];
                kC0 = *(const bfrag*)kp; kC1 = *(const bfrag*)(kp + 32);
            }
            kP0 = kC0; kP1 = kC1;
            for (int s = 0; s <= 8; ++s) {
                bfrag rN0 = rC0, rN1 = rC1, kN0 = kC0, kN1 = kC1;
                if (s < 8) {
                    const ushort_t* rp = &rh[(size_t)(tstart + jbase + (s + 1) * 16 + l15) * 768 + n * 64 + l4 * 8];
                    rN0 = *(const bfrag*)rp; rN1 = *(const bfrag*)(rp + 32);
                    if (s < 7) {
                        const ushort_t* kp = &kh[(size_t)(b * S_LEN + jbase + (s + 1) * 16 + l15) * 768 + n * 64 + l4 * 8];
                        kN0 = *(const bfrag*)kp; kN1 = *(const bfrag*)(kp + 32);
                    }
                }
                // pos tile s
                {
                    f32x4 pacc = {0, 0, 0, 0};
                    pacc = __builtin_amdgcn_mfma_f32_16x16x32_bf16(aQr0, rC0, pacc, 0, 0, 0);
                    pacc = __builtin_amdgcn_mfma_f32_16x16x32_bf16(aQr1, rC1, pacc, 0, 0, 0);
                    int tp = jbase + s * 16 + l15;
#pragma unroll
                    for (int rg = 0; rg < 4; ++rg) {
                        int il = l4 * 4 + rg;
                        int j = tp - 15 + il;
                        if ((unsigned)(j - jbase) < 128u)
                            sS[il * 1024 + (j ^ ((il & 7) << 3))] = f2bf(pacc[rg]);
                    }
                }
                // content tile s-1 + epilogue (masks from LDS)
                if (s >= 1) {
                    int j = jbase + (s - 1) * 16 + l15;
                    f32x4 cacc = {0, 0, 0, 0};
                    cacc = __builtin_amdgcn_mfma_f32_16x16x32_bf16(aQw0, kP0, cacc, 0, 0, 0);
                    cacc = __builtin_amdgcn_mfma_f32_16x16x32_bf16(aQw1, kP1, cacc, 0, 0, 0);
                    float am = bf2f(sAm[j]);
#pragma unroll
                    for (int rg = 0; rg < 4; ++rg) {
                        int il = l4 * 4 + rg;
                        int sidx = il * 1024 + (j ^ ((il & 7) << 3));
                        float pos = bf2f(sS[sidx]);
                        u64_t tw = sTT[il * 16 + (j >> 6)];
                        float ttv = ((tw >> (j & 63)) & 1ull) ? sameR[rg] : diffR[rg];
                        float cls = bf2f(sCls[sidx]);
                        float sc = cacc[rg] + (pos + ttv) * cls + am;
                        vmax[rg] = fmaxf(vmax[rg], sc);
                        sS[sidx] = f2bf(sc);
                    }
                }
                kP0 = kC0; kP1 = kC1;
                kC0 = kN0; kC1 = kN1;
                rC0 = rN0; rC1 = rN1;
            }
            // row-max across 16 lanes of each l4 group -> sMax[row][wave]
#pragma unroll
            for (int rg = 0; rg < 4; ++rg) {
#pragma unroll
                for (int off = 1; off < 16; off <<= 1)
                    vmax[rg] = fmaxf(vmax[rg], __shfl_xor(vmax[rg], off, 16));
            }
            if (l15 == 0) {
#pragma unroll
                for (int rg = 0; rg < 4; ++rg)
                    sMax[(l4 * 4 + rg) * 8 + w] = vmax[rg];
            }
        }
        __syncthreads();  // B2

        // ---- exp+sum pass: 32 threads per row ----
        {
            int row = tid >> 5, sub = tid & 31;
            float m = -3.0e38f;
#pragma unroll
            for (int q = 0; q < 8; ++q) m = fmaxf(m, sMax[row * 8 + q]);
            ushort_t* rp = &sS[row * 1024];
            float sum = 0.0f;
#pragma unroll
            for (int e = 0; e < 4; ++e) {
                int c = sub + 32 * e;
                bfrag v = *(const bfrag*)&rp[c * 8];
                bfrag st;
#pragma unroll
                for (int q = 0; q < 8; ++q) {
                    float ev = __expf(bf2f((ushort_t)v[q]) - m);
                    sum += ev;
                    st[q] = (short)f2bf(ev);
                }
                *(bfrag*)&rp[c * 8] = st;
            }
#pragma unroll
            for (int off = 1; off < 32; off <<= 1) sum += __shfl_xor(sum, off, 32);
            if (sub == 0) sSum[row] = sum;
        }
        __syncthreads();  // B3

        // ---- PV partials: wave w -> half=w>>2, cols (w&3)*16, 512 j ----
        {
            int half = w >> 2, c0 = (w & 3) * 16;
            const ushort_t* vbase = vt + ((size_t)(b * 768 + n * 64 + c0 + l15)) * 1024;
            f32x4 acc = {0, 0, 0, 0};
            bfrag vf[4];
#pragma unroll
            for (int q = 0; q < 4; ++q)
                vf[q] = *(const bfrag*)&vbase[(half * 16 + q) * 32 + l4 * 8];
            for (int blk = 0; blk < 4; ++blk) {
                bfrag cur[4];
#pragma unroll
                for (int q = 0; q < 4; ++q) cur[q] = vf[q];
                if (blk < 3) {
#pragma unroll
                    for (int q = 0; q < 4; ++q)
                        vf[q] = *(const bfrag*)&vbase[(half * 16 + (blk + 1) * 4 + q) * 32 + l4 * 8];
                }
#pragma unroll
                for (int q = 0; q < 4; ++q) {
                    int ks = half * 16 + blk * 4 + q;
                    bfrag pa = *(const bfrag*)&sS[l15 * 1024 + (((ks * 4 + l4) ^ (l15 & 7)) * 8)];
                    acc = __builtin_amdgcn_mfma_f32_16x16x32_bf16(pa, cur[q], acc, 0, 0, 0);
                }
            }
#pragma unroll
            for (int rg = 0; rg < 4; ++rg)
                sPV[half][l4 * 4 + rg][c0 + l15] = acc[rg];
        }
        __syncthreads();  // B4: sPV ready; next iteration combines + reuses sS
    }

    // ---- final combine (head hg*6+5) ----
    {
        const int npv = hg * 6 + 5;
        int e = tid * 2;
        int row = e >> 6, col = e & 63;
        float inv = 1.0f / sSum[row];
        float v0 = (sPV[0][row][col] + sPV[1][row][col]) * inv;
        float v1 = (sPV[0][row][col + 1] + sPV[1][row][col + 1]) * inv;
        uint_t pk = (uint_t)f2bf(v0) | ((uint_t)f2bf(v1) << 16);
        *(uint_t*)&av[(size_t)(b * S_LEN + i0 + row) * 768 + npv * 64 + col] = pk;
    }
}

// ---------------- residual + layernorm ----------------------------------
__global__ __launch_bounds__(256) void out_ln_kernel(
    const float* __restrict__ query, const float* __restrict__ attn_out,
    const float* __restrict__ g, const float* __restrict__ beta,
    float* __restrict__ out)
{
    __shared__ float sx[768];
    __shared__ float sRed[4];
    int row = blockIdx.x, tid = threadIdx.x;
    int wave = tid >> 6, lane = tid & 63;
    float lsum = 0.0f;
    for (int c = tid; c < 768; c += 256) {
        float x = query[(size_t)row * 768 + c] + attn_out[(size_t)row * 768 + c];
        sx[c] = x;
        lsum += x;
    }
#pragma unroll
    for (int off = 32; off >= 1; off >>= 1) lsum += __shfl_xor(lsum, off);
    if (lane == 0) sRed[wave] = lsum;
    __syncthreads();
    float mu = (sRed[0] + sRed[1] + sRed[2] + sRed[3]) * (1.0f / 768.0f);
    float lvar = 0.0f;
    for (int c = tid; c < 768; c += 256) {
        float d = sx[c] - mu;
        lvar += d * d;
    }
#pragma unroll
    for (int off = 32; off >= 1; off >>= 1) lvar += __shfl_xor(lvar, off);
    __syncthreads();
    if (lane == 0) sRed[wave] = lvar;
    __syncthreads();
    float var = (sRed[0] + sRed[1] + sRed[2] + sRed[3]) * (1.0f / 768.0f);
    float rstd = rsqrtf(var + 1e-9f);
    for (int c = tid; c < 768; c += 256)
        out[(size_t)row * 768 + c] = (sx[c] - mu) * rstd * g[c] + beta[c];
}

extern "C" void kernel_launch(void* const* d_in, const int* in_sizes, int n_in,
                              void* d_out, int out_size, void* d_ws, size_t ws_size,
                              hipStream_t stream)
{
    const float* query = (const float*)d_in[0];
    const float* key   = (const float*)d_in[1];
    const float* value = (const float*)d_in[2];
    const float* r     = (const float*)d_in[3];
    const float* cls_mask = (const float*)d_in[4];
    const int*   tt_mat   = (const int*)d_in[5];
    const int*   amask    = (const int*)d_in[6];
    const float* wq  = (const float*)d_in[7];
    const float* wk  = (const float*)d_in[8];
    const float* bk  = (const float*)d_in[9];
    const float* wv  = (const float*)d_in[10];
    const float* bv  = (const float*)d_in[11];
    const float* rwb = (const float*)d_in[12];
    const float* rrb = (const float*)d_in[13];
    const float* rsb = (const float*)d_in[14];
    const float* rk  = (const float*)d_in[15];
    const float* seg = (const float*)d_in[16];
    const float* wo  = (const float*)d_in[17];
    const float* bo  = (const float*)d_in[18];
    const float* lng = (const float*)d_in[19];
    const float* lnb = (const float*)d_in[20];
    float* out = (float*)d_out;

    char* W = (char*)d_ws;
    ushort_t* qwv = (ushort_t*)(W + 0);              // +3145728
    ushort_t* qrv = (ushort_t*)(W + 3145728);        // +3145728
    ushort_t* qsv = (ushort_t*)(W + 6291456);        // +3145728
    ushort_t* kh  = (ushort_t*)(W + 9437184);        // +3145728
    ushort_t* vt  = (ushort_t*)(W + 12582912);       // +3145728
    ushort_t* rh  = (ushort_t*)(W + 15728640);       // +3170304 (2064 rows)
    ushort_t* av  = (ushort_t*)(W + 18898944);       // +3145728
    ushort_t* wqT = (ushort_t*)(W + 22044672);       // +1179648
    ushort_t* wkT = (ushort_t*)(W + 23224320);
    ushort_t* wvT = (ushort_t*)(W + 24403968);
    ushort_t* rkT = (ushort_t*)(W + 25583616);
    ushort_t* woT = (ushort_t*)(W + 26763264);       // ends 27942912
    ushort_t* clsb = (ushort_t*)(W + 27942912);      // +2097152
    u64_t*    ttb  = (u64_t*)(W + 30040064);         // +262144 -> 30302208
    float* attn_out = (float*)(W + 0);               // aliases qwv..qsv (used after attn)

    hipLaunchKernelGGL(pack_masks, dim3(1024, 2), dim3(256), 0, stream,
                       cls_mask, tt_mat, clsb, ttb);

    TJobs tj;
    tj.src[0] = wq; tj.dst[0] = wqT;
    tj.src[1] = wk; tj.dst[1] = wkT;
    tj.src[2] = wv; tj.dst[2] = wvT;
    tj.src[3] = rk; tj.dst[3] = rkT;
    tj.src[4] = wo; tj.dst[4] = woT;
    hipLaunchKernelGGL(tcvt_multi, dim3(12, 12, 5), dim3(256), 0, stream, tj);

    GemmJobs4 pj;
    pj.j[0] = {query, nullptr, wqT, rwb, rrb, rsb, nullptr, qwv, qrv, qsv, SCALE, 3};
    pj.j[1] = {key,   nullptr, wkT, bk, nullptr, nullptr, nullptr, kh, nullptr, nullptr, 1.0f, 1};
    pj.j[2] = {value, nullptr, wvT, bv, nullptr, nullptr, nullptr, vt, nullptr, nullptr, 1.0f, 2};
    pj.j[3] = {r,     nullptr, rkT, nullptr, nullptr, nullptr, nullptr, rh, nullptr, nullptr, 1.0f, 1};
    hipLaunchKernelGGL(gemm_batch, dim3(32, 12, 4), dim3(256), 0, stream, pj);

    hipLaunchKernelGGL(attn_mfma, dim3(256), dim3(512), 0, stream,
                       qwv, qrv, qsv, kh, vt, rh, seg, clsb, ttb, amask, av);

    GemmJobs4 oj;
    oj.j[0] = {nullptr, av, woT, bo, nullptr, nullptr, attn_out, nullptr, nullptr, nullptr, 1.0f, 0};
    oj.j[1] = oj.j[0]; oj.j[2] = oj.j[0]; oj.j[3] = oj.j[0];
    hipLaunchKernelGGL(gemm_batch, dim3(32, 12, 1), dim3(256), 0, stream, oj);

    hipLaunchKernelGGL(out_ln_kernel, dim3(2048), dim3(256), 0, stream,
                       query, attn_out, lng, lnb, out);
}